// Round 4
// baseline (184.937 us; speedup 1.0000x reference)
//
#include <hip/hip_runtime.h>

#define N_  4096
#define D_  64
#define C_  256

typedef short bf16x8 __attribute__((ext_vector_type(8)));
typedef float f32x4  __attribute__((ext_vector_type(4)));

__device__ __forceinline__ unsigned short f2bf(float f) {
    union { float f; unsigned int i; } v; v.f = f;
    unsigned int r = v.i + 0x7fffu + ((v.i >> 16) & 1u);
    return (unsigned short)(r >> 16);
}

// ---------- fused prepass (no LDS, max occupancy) ----------
// blocks [0,256): q->bf16 ; [256,512): pg->bf16 ;
// blocks [512, 512+2048): v -> vt2 in MFMA-B-frag order, ONE WAVE PER FRAGMENT.
//   frag f = ((b*32 + jt)*16 + cb)*4 + ks  (512 shorts, contiguous 1KB)
//   vt2[f*512 + lane*8 + e] = v[b][jt*128 + ks*32 + (lane>>4)*8 + e][cb*16 + (lane&15)]
__global__ void prepass_kernel(const float* __restrict__ xq,
                               const float* __restrict__ pg,
                               const float* __restrict__ xv,
                               unsigned short* __restrict__ qbf,
                               unsigned short* __restrict__ pgbf,
                               unsigned short* __restrict__ vt2) {
    const int bid = blockIdx.x;
    const int t   = threadIdx.x;
    if (bid < 512) {
        const float* src = (bid < 256) ? xq : pg;
        unsigned short* dst = (bid < 256) ? qbf : pgbf;
        const int base = (bid & 255) * 1024 + t;
#pragma unroll
        for (int it = 0; it < 4; ++it) {
            const int i = base + it * 256;
            float4 v = ((const float4*)src)[i];
            ushort4 o;
            o.x = f2bf(v.x); o.y = f2bf(v.y); o.z = f2bf(v.z); o.w = f2bf(v.w);
            ((ushort4*)dst)[i] = o;
        }
        return;
    }
    // V fragment emit: 4 waves/block, one frag per wave
    const int lane = t & 63;
    const int w    = t >> 6;
    const int l15  = lane & 15;
    const int quad = lane >> 4;
    const int f    = (bid - 512) * 4 + w;        // 0..8191
    const int b    = f >> 11;
    const int jt   = (f >> 6) & 31;
    const int cb   = (f >> 2) & 15;
    const int ks   = f & 3;
    const int c    = cb * 16 + l15;
    const int jb   = jt * 128 + ks * 32 + quad * 8;
    const float* src = xv + ((size_t)b * N_ + jb) * C_ + c;
    float v0 = src[0 * C_], v1 = src[1 * C_], v2 = src[2 * C_], v3 = src[3 * C_];
    float v4 = src[4 * C_], v5 = src[5 * C_], v6 = src[6 * C_], v7 = src[7 * C_];
    uint4 o;
    o.x = (unsigned)f2bf(v0) | ((unsigned)f2bf(v1) << 16);
    o.y = (unsigned)f2bf(v2) | ((unsigned)f2bf(v3) << 16);
    o.z = (unsigned)f2bf(v4) | ((unsigned)f2bf(v5) << 16);
    o.w = (unsigned)f2bf(v6) | ((unsigned)f2bf(v7) << 16);
    *(uint4*)(vt2 + (size_t)f * 512 + lane * 8) = o;
}

// ---------- main: 256 blocks x 512 thr (8 waves), M=64, j-tile 128 ----------
// Swapped-S (as R3) + 2-D wave split for PV: wave w = (jq=w>>1, ch2=w&1)
//   owns j-quarter (32 j = ONE K=32 slice) x 128-ch half.
//   -> each wave reads only 4KB of P per jt (4 ds_read_b128, was 16).
//   LDS loop traffic 144KB -> 48KB per jt. S/exp not duplicated (each wave
//   still computes its own 16-j strip). O-partial 64x128/wave (128 VGPR);
//   4-way merge tree through LDS once at the end + vectorized epilogue.
__global__ __launch_bounds__(512, 2) void attn_main(
    const float* __restrict__ g,  const float* __restrict__ x,
    const float* __restrict__ kk, float* __restrict__ out,
    const unsigned short* __restrict__ qbf,
    const unsigned short* __restrict__ pgbf,
    const unsigned short* __restrict__ vt2)
{
    // loop: pb0/pb1 = 2 x 32KB P buffers (XOR-swizzled).
    // merge: 4 regions of [64][140] f32 (35840 B each), reusing same space.
    __shared__ __align__(16) unsigned char smem[143360];
    __shared__ float s_l[64];

    const int t    = threadIdx.x;
    const int lane = t & 63;
    const int w    = t >> 6;
    const int l15  = lane & 15;
    const int quad = lane >> 4;
    const int swz  = (l15 & 7) << 4;
    const int jq   = w >> 1;            // j-quarter 0..3
    const int ch2  = w & 1;             // 128-ch half 0..1

    const int bid = blockIdx.x;
    const int b   = bid & 3;            // batch pinned to 2 XCDs
    const int rg  = bid >> 2;           // 0..63
    const int i0  = rg * 64;
    const size_t rowbase = (size_t)b * N_ + i0;

    if (t < 64) s_l[t] = 0.f;

    // ---- g passthrough: 64 rows x 256 ch ----
#pragma unroll
    for (int it = 0; it < 8; ++it) {
        const int row = it * 8 + w;
        const int c4  = lane * 4;
        const float4 gv = *(const float4*)(g + (rowbase + row) * C_ + c4);
        *(float4*)(out + (rowbase + row) * (2 * C_) + C_ + c4) = gv;
    }

    // ---- pg B-frags: 4 i-tiles x 2 K-slices, persistent ----
    bf16x8 pgf[4][2];
#pragma unroll
    for (int nt = 0; nt < 4; ++nt)
#pragma unroll
        for (int ks = 0; ks < 2; ++ks)
            pgf[nt][ks] = *(const bf16x8*)(pgbf +
                (rowbase + nt * 16 + l15) * D_ + ks * 32 + quad * 8);

    f32x4 oacc[4][8];                   // [mt][ct]: 64 rows x this wave's 128-ch half
#pragma unroll
    for (int mt = 0; mt < 4; ++mt)
#pragma unroll
        for (int ct = 0; ct < 8; ++ct)
            oacc[mt][ct] = (f32x4){0.f, 0.f, 0.f, 0.f};
    float ls[4] = {0.f, 0.f, 0.f, 0.f};

    const unsigned short* qb  = qbf + (size_t)b * N_ * D_;
    const unsigned short* vtb = vt2 + (size_t)b * N_ * C_;
    unsigned short* const pb0 = (unsigned short*)smem;
    unsigned short* const pb1 = (unsigned short*)(smem + 32768);

    auto load_q = [&](bf16x8 (&qf)[2], int jt) {
#pragma unroll
        for (int ks = 0; ks < 2; ++ks)
            qf[ks] = *(const bf16x8*)(qb +
                (size_t)(jt * 128 + w * 16 + l15) * D_ + ks * 32 + quad * 8);
    };
    // V frags for this wave: ks = jq, cb = ch2*8 + ct  (each frag read by ONE wave)
    auto load_v = [&](bf16x8 (&vf)[8], int jt) {
        const unsigned short* tbase = vtb +
            ((size_t)(jt * 16 + ch2 * 8) * 4 + jq) * 512 + (size_t)lane * 8;
#pragma unroll
        for (int ct = 0; ct < 8; ++ct)
            vf[ct] = *(const bf16x8*)(tbase + (size_t)ct * 2048);
    };
    // S for one jt: 8 MFMA -> exp -> 4x ds_write_b64 (transposed+swz)
    auto s_step = [&](const bf16x8 (&qf)[2], unsigned short* pbuf) {
        f32x4 sacc[4];
#pragma unroll
        for (int nt = 0; nt < 4; ++nt) sacc[nt] = (f32x4){0.f,0.f,0.f,0.f};
#pragma unroll
        for (int ks = 0; ks < 2; ++ks)
#pragma unroll
            for (int nt = 0; nt < 4; ++nt)
                sacc[nt] = __builtin_amdgcn_mfma_f32_16x16x32_bf16(
                    qf[ks], pgf[nt][ks], sacc[nt], 0, 0, 0);
#pragma unroll
        for (int nt = 0; nt < 4; ++nt) {
            const float p0 = __expf(sacc[nt][0]);
            const float p1 = __expf(sacc[nt][1]);
            const float p2 = __expf(sacc[nt][2]);
            const float p3 = __expf(sacc[nt][3]);
            ls[nt] += (p0 + p1) + (p2 + p3);
            ushort4 pk;
            pk.x = f2bf(p0); pk.y = f2bf(p1); pk.z = f2bf(p2); pk.w = f2bf(p3);
            const int wb = ((nt * 16 + l15) * 256 + (w * 16 + quad * 4) * 2) ^ swz;
            *(ushort4*)((char*)pbuf + wb) = pk;
        }
    };
    // PV for one jt: 4x ds_read_b128 (this wave's j-quarter) + 32 MFMA
    auto pv_step = [&](const bf16x8 (&vf)[8], const unsigned short* pbuf) {
        bf16x8 pa[4];
#pragma unroll
        for (int mt = 0; mt < 4; ++mt) {
            const int rb = ((mt * 16 + l15) * 256 + jq * 64 + quad * 16) ^ swz;
            pa[mt] = *(const bf16x8*)((const char*)pbuf + rb);
        }
#pragma unroll
        for (int ct = 0; ct < 8; ++ct)
#pragma unroll
            for (int mt = 0; mt < 4; ++mt)
                oacc[mt][ct] = __builtin_amdgcn_mfma_f32_16x16x32_bf16(
                    pa[mt], vf[ct], oacc[mt][ct], 0, 0, 0);
    };

    bf16x8 qfA[2], qfB[2], vf[8];

    // ---- prologue: S(0) -> buf0 ----
    load_q(qfA, 0);
    s_step(qfA, pb0);
    load_q(qfB, 1);
    __syncthreads();

    // ---- pipelined main loop: phase p does { V(p), q(p+2), S(p+1), PV(p) } ----
#pragma unroll 1
    for (int jtp = 0; jtp < 15; ++jtp) {
        const int p = 2 * jtp;
        // even phase
        load_v(vf, p);
        load_q(qfA, p + 2);
        s_step(qfB, pb1);               // S(p+1) -> buf1
        pv_step(vf, pb0);               // PV(p) from buf0
        __syncthreads();
        // odd phase
        load_v(vf, p + 1);
        load_q(qfB, p + 3);
        s_step(qfA, pb0);               // S(p+2) -> buf0
        pv_step(vf, pb1);               // PV(p+1) from buf1
        __syncthreads();
    }
    // tail: phase 30 then 31
    load_v(vf, 30);
    s_step(qfB, pb1);                   // S(31) -> buf1
    pv_step(vf, pb0);                   // PV(30)
    __syncthreads();
    load_v(vf, 31);
    pv_step(vf, pb1);                   // PV(31)

    // ---- l reduction: lane holds i=nt*16+l15; sum quads then waves ----
#pragma unroll
    for (int nt = 0; nt < 4; ++nt) {
        float s = ls[nt];
        s += __shfl_xor(s, 16);
        s += __shfl_xor(s, 32);
        if (lane < 16) atomicAdd(&s_l[nt * 16 + lane], s);
    }
    __syncthreads();   // also guards smem reuse below

    // ---- O merge tree over jq (4 copies per (row, ch-half)) ----
    // region(ap, bp) = smem + (ap*2+bp)*35840, layout [64][140] f32
    // step1: jq 2,3 write; step2: jq 0,1 add; step3: jq1 write; step4: jq0 add+final
    if (jq >= 2) {
        float* Rg = (float*)(smem + (size_t)((jq - 2) * 2 + ch2) * 35840);
#pragma unroll
        for (int mt = 0; mt < 4; ++mt)
#pragma unroll
            for (int ct = 0; ct < 8; ++ct)
#pragma unroll
                for (int r = 0; r < 4; ++r)
                    Rg[(mt * 16 + quad * 4 + r) * 140 + ct * 16 + l15] = oacc[mt][ct][r];
    }
    __syncthreads();
    if (jq < 2) {
        const float* Rg = (const float*)(smem + (size_t)(jq * 2 + ch2) * 35840);
#pragma unroll
        for (int mt = 0; mt < 4; ++mt)
#pragma unroll
            for (int ct = 0; ct < 8; ++ct)
#pragma unroll
                for (int r = 0; r < 4; ++r)
                    oacc[mt][ct][r] += Rg[(mt * 16 + quad * 4 + r) * 140 + ct * 16 + l15];
    }
    __syncthreads();
    if (jq == 1) {
        float* Rg = (float*)(smem + (size_t)(0 * 2 + ch2) * 35840);
#pragma unroll
        for (int mt = 0; mt < 4; ++mt)
#pragma unroll
            for (int ct = 0; ct < 8; ++ct)
#pragma unroll
                for (int r = 0; r < 4; ++r)
                    Rg[(mt * 16 + quad * 4 + r) * 140 + ct * 16 + l15] = oacc[mt][ct][r];
    }
    __syncthreads();
    if (jq == 0) {
        const float* Rg0 = (const float*)(smem + (size_t)(0 * 2 + ch2) * 35840);
        float* Rg1 = (float*)(smem + (size_t)(1 * 2 + ch2) * 35840);
#pragma unroll
        for (int mt = 0; mt < 4; ++mt)
#pragma unroll
            for (int ct = 0; ct < 8; ++ct)
#pragma unroll
                for (int r = 0; r < 4; ++r) {
                    const int idx = (mt * 16 + quad * 4 + r) * 140 + ct * 16 + l15;
                    Rg1[idx] = oacc[mt][ct][r] + Rg0[idx];
                }
    }
    __syncthreads();

    // ---- epilogue: wave w owns rows w*8..w*8+7, fully vectorized ----
    const float kval = kk[0];
    const int row  = w * 8 + (lane >> 3);
    const float linv = 1.f / s_l[row];
    const size_t rr = rowbase + row;
#pragma unroll
    for (int b2 = 0; b2 < 2; ++b2) {
        const float* Rf = (const float*)(smem + (size_t)(2 + b2) * 35840);
#pragma unroll
        for (int u = 0; u < 4; ++u) {
            const int cl = (lane & 7) * 4 + u * 32;
            const f32x4 ov = *(const f32x4*)&Rf[row * 140 + cl];
            const int c = b2 * 128 + cl;
            const float4 xv4 = *(const float4*)(x + rr * C_ + c);
            float4 o4;
            o4.x = kval * (ov[0] * linv) + xv4.x;
            o4.y = kval * (ov[1] * linv) + xv4.y;
            o4.z = kval * (ov[2] * linv) + xv4.z;
            o4.w = kval * (ov[3] * linv) + xv4.w;
            *(float4*)(out + rr * (2 * C_) + c) = o4;
        }
    }
}

// ---------- fallback (round-2 vector kernel) if workspace too small ----------
#define ROWS 4
#define FNT  256
__global__ __launch_bounds__(FNT, 2) void attn_fallback(
    const float* __restrict__ g, const float* __restrict__ x,
    const float* __restrict__ xq, const float* __restrict__ pg,
    const float* __restrict__ xv, const float* __restrict__ kk,
    float* __restrict__ out)
{
    __shared__ __align__(16) float s_pg[ROWS][D_];
    __shared__ __align__(16) float s_sc[N_ * ROWS];
    __shared__ float s_rmax[4][ROWS];
    __shared__ float s_rsum[4][ROWS];

    const int t = threadIdx.x, lane = t & 63, w = t >> 6, blk = blockIdx.x;
    const int b = blk >> 10, i0 = (blk & 1023) * ROWS;
    const size_t rowbase = (size_t)b * N_ + i0;
    {
        const int r = t >> 6, cc = (t & 63) * 4;
        const float4 gv = *(const float4*)(g + (rowbase + r) * C_ + cc);
        *(float4*)(out + (rowbase + r) * (2 * C_) + C_ + cc) = gv;
    }
    { const int r = t >> 6, d = t & 63; s_pg[r][d] = pg[(rowbase + r) * D_ + d]; }
    __syncthreads();
    const float* qb = xq + (size_t)b * N_ * D_;
    float lmax[ROWS];
#pragma unroll
    for (int r = 0; r < ROWS; ++r) lmax[r] = -1e30f;
    for (int jj = 0; jj < N_ / FNT; ++jj) {
        const int j = t + jj * FNT;
        const float4* q4p = (const float4*)(qb + (size_t)j * D_);
        float s[ROWS] = {0.f, 0.f, 0.f, 0.f};
#pragma unroll
        for (int u = 0; u < D_ / 8; ++u) {
            const float4 qa = q4p[u * 2], qc = q4p[u * 2 + 1];
#pragma unroll
            for (int r = 0; r < ROWS; ++r) {
                const float4 pa = *(const float4*)&s_pg[r][u * 8];
                const float4 pb = *(const float4*)&s_pg[r][u * 8 + 4];
                s[r] += qa.x * pa.x + qa.y * pa.y + qa.z * pa.z + qa.w * pa.w
                      + qc.x * pb.x + qc.y * pb.y + qc.z * pb.z + qc.w * pb.w;
            }
        }
        *(float4*)&s_sc[j * ROWS] = make_float4(s[0], s[1], s[2], s[3]);
#pragma unroll
        for (int r = 0; r < ROWS; ++r) lmax[r] = fmaxf(lmax[r], s[r]);
    }
#pragma unroll
    for (int r = 0; r < ROWS; ++r) {
        float m = lmax[r];
        for (int o = 32; o > 0; o >>= 1) m = fmaxf(m, __shfl_down(m, o));
        if (lane == 0) s_rmax[w][r] = m;
    }
    __syncthreads();
    float bmax[ROWS];
#pragma unroll
    for (int r = 0; r < ROWS; ++r)
        bmax[r] = fmaxf(fmaxf(s_rmax[0][r], s_rmax[1][r]), fmaxf(s_rmax[2][r], s_rmax[3][r]));
    float lsum[ROWS] = {0.f, 0.f, 0.f, 0.f};
    for (int jj = 0; jj < N_ / FNT; ++jj) {
        const int j = t + jj * FNT;
        float4 s4 = *(const float4*)&s_sc[j * ROWS];
        s4.x = __expf(s4.x - bmax[0]); s4.y = __expf(s4.y - bmax[1]);
        s4.z = __expf(s4.z - bmax[2]); s4.w = __expf(s4.w - bmax[3]);
        *(float4*)&s_sc[j * ROWS] = s4;
        lsum[0] += s4.x; lsum[1] += s4.y; lsum[2] += s4.z; lsum[3] += s4.w;
    }
#pragma unroll
    for (int r = 0; r < ROWS; ++r) {
        float sm = lsum[r];
        for (int o = 32; o > 0; o >>= 1) sm += __shfl_down(sm, o);
        if (lane == 0) s_rsum[w][r] = sm;
    }
    __syncthreads();
    float rinv[ROWS];
#pragma unroll
    for (int r = 0; r < ROWS; ++r)
        rinv[r] = 1.f / (s_rsum[0][r] + s_rsum[1][r] + s_rsum[2][r] + s_rsum[3][r]);
    const int jg = lane >> 4;
    const int c0 = (w * 16 + (lane & 15)) * 4;
    const float* vb = xv + (size_t)b * N_ * C_;
    float acc[ROWS][4];
#pragma unroll
    for (int r = 0; r < ROWS; ++r)
#pragma unroll
        for (int q = 0; q < 4; ++q) acc[r][q] = 0.f;
#pragma unroll 4
    for (int jj = 0; jj < N_ / 4; ++jj) {
        const int j = jj * 4 + jg;
        const float4 p4 = *(const float4*)&s_sc[j * ROWS];
        const float4 v4 = *(const float4*)(vb + (size_t)j * C_ + c0);
        acc[0][0] += p4.x * v4.x; acc[0][1] += p4.x * v4.y; acc[0][2] += p4.x * v4.z; acc[0][3] += p4.x * v4.w;
        acc[1][0] += p4.y * v4.x; acc[1][1] += p4.y * v4.y; acc[1][2] += p4.y * v4.z; acc[1][3] += p4.y * v4.w;
        acc[2][0] += p4.z * v4.x; acc[2][1] += p4.z * v4.y; acc[2][2] += p4.z * v4.z; acc[2][3] += p4.z * v4.w;
        acc[3][0] += p4.w * v4.x; acc[3][1] += p4.w * v4.y; acc[3][2] += p4.w * v4.z; acc[3][3] += p4.w * v4.w;
    }
#pragma unroll
    for (int r = 0; r < ROWS; ++r)
#pragma unroll
        for (int q = 0; q < 4; ++q) {
            acc[r][q] += __shfl_xor(acc[r][q], 16);
            acc[r][q] += __shfl_xor(acc[r][q], 32);
        }
    const float kval = kk[0];
    if (lane < 16) {
        const int c = (w * 16 + lane) * 4;
#pragma unroll
        for (int r = 0; r < ROWS; ++r) {
            const float4 xv4 = *(const float4*)(x + (rowbase + r) * C_ + c);
            float4 ov;
            ov.x = kval * (acc[r][0] * rinv[r]) + xv4.x;
            ov.y = kval * (acc[r][1] * rinv[r]) + xv4.y;
            ov.z = kval * (acc[r][2] * rinv[r]) + xv4.z;
            ov.w = kval * (acc[r][3] * rinv[r]) + xv4.w;
            *(float4*)(out + (rowbase + r) * (2 * C_) + c) = ov;
        }
    }
}

extern "C" void kernel_launch(void* const* d_in, const int* in_sizes, int n_in,
                              void* d_out, int out_size, void* d_ws, size_t ws_size,
                              hipStream_t stream) {
    const float* g  = (const float*)d_in[0];
    const float* x  = (const float*)d_in[1];
    const float* xq = (const float*)d_in[2];
    const float* pg = (const float*)d_in[3];
    const float* xv = (const float*)d_in[4];
    const float* kk = (const float*)d_in[5];
    float* out = (float*)d_out;

    const int B = in_sizes[0] / (N_ * C_);   // 4
    const size_t qn = (size_t)B * N_ * D_;
    const size_t vn = (size_t)B * N_ * C_;
    const size_t need = (2 * qn + vn) * sizeof(unsigned short);

    if (B != 4 || ws_size < need) {
        attn_fallback<<<dim3(B * (N_ / ROWS)), FNT, 0, stream>>>(g, x, xq, pg, xv, kk, out);
        return;
    }

    unsigned short* qbf  = (unsigned short*)d_ws;
    unsigned short* pgbf = qbf + qn;
    unsigned short* vt2  = pgbf + qn;

    prepass_kernel<<<dim3(512 + B * 512), 256, 0, stream>>>(xq, pg, xv, qbf, pgbf, vt2);
    attn_main<<<dim3(B * (N_ / 64)), 512, 0, stream>>>(g, x, kk, out, qbf, pgbf, vt2);
}

// Round 5
// 160.435 us; speedup vs baseline: 1.1527x; 1.1527x over previous
//
#include <hip/hip_runtime.h>

#define N_  4096
#define D_  64
#define C_  256

typedef short bf16x8 __attribute__((ext_vector_type(8)));
typedef float f32x4  __attribute__((ext_vector_type(4)));

__device__ __forceinline__ unsigned short f2bf(float f) {
    union { float f; unsigned int i; } v; v.f = f;
    unsigned int r = v.i + 0x7fffu + ((v.i >> 16) & 1u);
    return (unsigned short)(r >> 16);
}

// ---------- fused prepass (no LDS, max occupancy) ----------
// blocks [0,256): q->bf16 ; [256,512): pg->bf16 ;
// blocks [512, 512+2048): v -> vt2 in MFMA-B-frag order, ONE WAVE PER FRAGMENT.
//   frag f = ((b*32 + jt)*16 + cb)*4 + ks  (512 shorts, contiguous 1KB)
//   vt2[f*512 + lane*8 + e] = v[b][jt*128 + ks*32 + (lane>>4)*8 + e][cb*16 + (lane&15)]
__global__ void prepass_kernel(const float* __restrict__ xq,
                               const float* __restrict__ pg,
                               const float* __restrict__ xv,
                               unsigned short* __restrict__ qbf,
                               unsigned short* __restrict__ pgbf,
                               unsigned short* __restrict__ vt2) {
    const int bid = blockIdx.x;
    const int t   = threadIdx.x;
    if (bid < 512) {
        const float* src = (bid < 256) ? xq : pg;
        unsigned short* dst = (bid < 256) ? qbf : pgbf;
        const int base = (bid & 255) * 1024 + t;
#pragma unroll
        for (int it = 0; it < 4; ++it) {
            const int i = base + it * 256;
            float4 v = ((const float4*)src)[i];
            ushort4 o;
            o.x = f2bf(v.x); o.y = f2bf(v.y); o.z = f2bf(v.z); o.w = f2bf(v.w);
            ((ushort4*)dst)[i] = o;
        }
        return;
    }
    // V fragment emit: 4 waves/block, one frag per wave
    const int lane = t & 63;
    const int w    = t >> 6;
    const int l15  = lane & 15;
    const int quad = lane >> 4;
    const int f    = (bid - 512) * 4 + w;        // 0..8191
    const int b    = f >> 11;
    const int jt   = (f >> 6) & 31;
    const int cb   = (f >> 2) & 15;
    const int ks   = f & 3;
    const int c    = cb * 16 + l15;
    const int jb   = jt * 128 + ks * 32 + quad * 8;
    const float* src = xv + ((size_t)b * N_ + jb) * C_ + c;
    float v0 = src[0 * C_], v1 = src[1 * C_], v2 = src[2 * C_], v3 = src[3 * C_];
    float v4 = src[4 * C_], v5 = src[5 * C_], v6 = src[6 * C_], v7 = src[7 * C_];
    uint4 o;
    o.x = (unsigned)f2bf(v0) | ((unsigned)f2bf(v1) << 16);
    o.y = (unsigned)f2bf(v2) | ((unsigned)f2bf(v3) << 16);
    o.z = (unsigned)f2bf(v4) | ((unsigned)f2bf(v5) << 16);
    o.w = (unsigned)f2bf(v6) | ((unsigned)f2bf(v7) << 16);
    *(uint4*)(vt2 + (size_t)f * 512 + lane * 8) = o;
}

// ---------- main: 256 blocks x 512 thr (8 waves), M=64, j-tile 128 ----------
// Swapped-S (R3) + 2-D wave split sized for the register budget:
//   wave w = (jh=w>>2, ch4=w&3) owns j-half (64 j = 2 K-slices) x 64-ch quarter.
//   -> 8 ds_read_b128 of P per wave per jt (R3: 16), read:MFMA = 1:4.
//   -> oacc[4][4] = 64 VGPR (R4's 128-VGPR oacc spilled; this fits).
//   V double-buffered a full phase ahead (R3 schedule). Each V frag still
//   read by exactly one wave. O merge: single 2-way step over jh + vectorized
//   float4 epilogue, reusing P-buffer LDS after the loop.
__global__ __launch_bounds__(512, 2) void attn_main(
    const float* __restrict__ g,  const float* __restrict__ x,
    const float* __restrict__ kk, float* __restrict__ out,
    const unsigned short* __restrict__ qbf,
    const unsigned short* __restrict__ pgbf,
    const unsigned short* __restrict__ vt2)
{
    // loop: pb0/pb1 = 2 x 16KB P buffers (XOR-swizzled), at smem[0..32768)
    // merge: 4 regions of [64][68] f32 (17408 B each) = 69632 B, reused space
    __shared__ __align__(16) unsigned char smem[69632];
    __shared__ float s_l[64];

    const int t    = threadIdx.x;
    const int lane = t & 63;
    const int w    = t >> 6;
    const int l15  = lane & 15;
    const int quad = lane >> 4;
    const int swz  = (l15 & 7) << 4;
    const int jh   = w >> 2;            // j-half 0..1
    const int ch4  = w & 3;             // 64-ch quarter 0..3

    const int bid = blockIdx.x;
    const int b   = bid & 3;            // batch pinned to 2 XCDs
    const int rg  = bid >> 2;           // 0..63
    const int i0  = rg * 64;
    const size_t rowbase = (size_t)b * N_ + i0;

    if (t < 64) s_l[t] = 0.f;

    // ---- g passthrough: 64 rows x 256 ch ----
#pragma unroll
    for (int it = 0; it < 8; ++it) {
        const int row = it * 8 + w;
        const int c4  = lane * 4;
        const float4 gv = *(const float4*)(g + (rowbase + row) * C_ + c4);
        *(float4*)(out + (rowbase + row) * (2 * C_) + C_ + c4) = gv;
    }

    // ---- pg B-frags: 4 i-tiles x 2 K-slices, persistent ----
    bf16x8 pgf[4][2];
#pragma unroll
    for (int nt = 0; nt < 4; ++nt)
#pragma unroll
        for (int ks = 0; ks < 2; ++ks)
            pgf[nt][ks] = *(const bf16x8*)(pgbf +
                (rowbase + nt * 16 + l15) * D_ + ks * 32 + quad * 8);

    f32x4 oacc[4][4];                   // [mt][ct]: 64 rows x this wave's 64-ch quarter
#pragma unroll
    for (int mt = 0; mt < 4; ++mt)
#pragma unroll
        for (int ct = 0; ct < 4; ++ct)
            oacc[mt][ct] = (f32x4){0.f, 0.f, 0.f, 0.f};
    float ls[4] = {0.f, 0.f, 0.f, 0.f};

    const unsigned short* qb  = qbf + (size_t)b * N_ * D_;
    const unsigned short* vtb = vt2 + (size_t)b * N_ * C_;
    unsigned short* const pb0 = (unsigned short*)smem;
    unsigned short* const pb1 = (unsigned short*)(smem + 16384);

    auto load_q = [&](bf16x8 (&qf)[2], int jt) {
#pragma unroll
        for (int ks = 0; ks < 2; ++ks)
            qf[ks] = *(const bf16x8*)(qb +
                (size_t)(jt * 128 + w * 16 + l15) * D_ + ks * 32 + quad * 8);
    };
    // V frags for this wave: ks = jh*2+ks2, cb = ch4*4+ct (each frag -> ONE wave)
    auto load_v = [&](bf16x8 (&vf)[2][4], int jt) {
#pragma unroll
        for (int ks2 = 0; ks2 < 2; ++ks2)
#pragma unroll
            for (int ct = 0; ct < 4; ++ct)
                vf[ks2][ct] = *(const bf16x8*)(vtb +
                    ((size_t)(jt * 16 + ch4 * 4 + ct) * 4 + (jh * 2 + ks2)) * 512 +
                    (size_t)lane * 8);
    };
    // S for one jt: 8 MFMA -> exp -> 4x ds_write_b64 (transposed+swz)
    auto s_step = [&](const bf16x8 (&qf)[2], unsigned short* pbuf) {
        f32x4 sacc[4];
#pragma unroll
        for (int nt = 0; nt < 4; ++nt) sacc[nt] = (f32x4){0.f,0.f,0.f,0.f};
#pragma unroll
        for (int ks = 0; ks < 2; ++ks)
#pragma unroll
            for (int nt = 0; nt < 4; ++nt)
                sacc[nt] = __builtin_amdgcn_mfma_f32_16x16x32_bf16(
                    qf[ks], pgf[nt][ks], sacc[nt], 0, 0, 0);
#pragma unroll
        for (int nt = 0; nt < 4; ++nt) {
            const float p0 = __expf(sacc[nt][0]);
            const float p1 = __expf(sacc[nt][1]);
            const float p2 = __expf(sacc[nt][2]);
            const float p3 = __expf(sacc[nt][3]);
            ls[nt] += (p0 + p1) + (p2 + p3);
            ushort4 pk;
            pk.x = f2bf(p0); pk.y = f2bf(p1); pk.z = f2bf(p2); pk.w = f2bf(p3);
            const int wb = ((nt * 16 + l15) * 256 + (w * 16 + quad * 4) * 2) ^ swz;
            *(ushort4*)((char*)pbuf + wb) = pk;
        }
    };
    // PV for one jt: 8x ds_read_b128 (this wave's j-half) + 32 MFMA
    auto pv_step = [&](const bf16x8 (&vf)[2][4], const unsigned short* pbuf) {
#pragma unroll
        for (int ks2 = 0; ks2 < 2; ++ks2) {
            const int ks = jh * 2 + ks2;
            bf16x8 pa[4];
#pragma unroll
            for (int mt = 0; mt < 4; ++mt) {
                const int rb = ((mt * 16 + l15) * 256 + ks * 64 + quad * 16) ^ swz;
                pa[mt] = *(const bf16x8*)((const char*)pbuf + rb);
            }
#pragma unroll
            for (int ct = 0; ct < 4; ++ct)
#pragma unroll
                for (int mt = 0; mt < 4; ++mt)
                    oacc[mt][ct] = __builtin_amdgcn_mfma_f32_16x16x32_bf16(
                        pa[mt], vf[ks2][ct], oacc[mt][ct], 0, 0, 0);
        }
    };

    bf16x8 qfA[2], qfB[2], vfA[2][4], vfB[2][4];

    // ---- prologue: S(0) -> buf0 ----
    load_q(qfA, 0);
    load_v(vfA, 0);
    s_step(qfA, pb0);
    load_q(qfB, 1);
    __syncthreads();

    // ---- pipelined main loop: 2 jt per iteration ----
#pragma unroll 1
    for (int jtp = 0; jtp < 15; ++jtp) {
        const int p = 2 * jtp;
        // even phase: PV(p) + S(p+1)
        load_v(vfB, p + 1);
        load_q(qfA, p + 2);
        s_step(qfB, pb1);
        pv_step(vfA, pb0);
        __syncthreads();
        // odd phase: PV(p+1) + S(p+2)
        load_v(vfA, p + 2);
        load_q(qfB, p + 3);
        s_step(qfA, pb0);
        pv_step(vfB, pb1);
        __syncthreads();
    }
    // tail: jt=30 then jt=31
    load_v(vfB, 31);
    s_step(qfB, pb1);
    pv_step(vfA, pb0);
    __syncthreads();
    pv_step(vfB, pb1);

    // ---- l reduction: lane holds i=nt*16+l15; sum quads then waves ----
#pragma unroll
    for (int nt = 0; nt < 4; ++nt) {
        float s = ls[nt];
        s += __shfl_xor(s, 16);
        s += __shfl_xor(s, 32);
        if (lane < 16) atomicAdd(&s_l[nt * 16 + lane], s);
    }
    __syncthreads();   // P buffers dead; smem reused for merge below

    // ---- O merge over jh: jh=1 writes, jh=0 adds ----
    // region ch4: [64][68] f32 at smem + ch4*17408
    {
        float* Rg = (float*)(smem + (size_t)ch4 * 17408);
        if (jh == 1) {
#pragma unroll
            for (int mt = 0; mt < 4; ++mt)
#pragma unroll
                for (int ct = 0; ct < 4; ++ct)
#pragma unroll
                    for (int r = 0; r < 4; ++r)
                        Rg[(mt * 16 + quad * 4 + r) * 68 + ct * 16 + l15] = oacc[mt][ct][r];
        }
        __syncthreads();
        if (jh == 0) {
#pragma unroll
            for (int mt = 0; mt < 4; ++mt)
#pragma unroll
                for (int ct = 0; ct < 4; ++ct)
#pragma unroll
                    for (int r = 0; r < 4; ++r) {
                        const int idx = (mt * 16 + quad * 4 + r) * 68 + ct * 16 + l15;
                        Rg[idx] += oacc[mt][ct][r];
                    }
        }
        __syncthreads();
    }

    // ---- epilogue: vectorized, 4096 float4 over 512 threads ----
    const float kval = kk[0];
#pragma unroll
    for (int it = 0; it < 8; ++it) {
        const int idx = it * 512 + t;       // 0..4095
        const int row = idx >> 6;           // 64 float4-cols per row
        const int cq  = idx & 63;
        const int c   = cq * 4;
        const float* Rg = (const float*)(smem + (size_t)(cq >> 4) * 17408);
        const f32x4 ov = *(const f32x4*)&Rg[row * 68 + (cq & 15) * 4];
        const float linv = 1.f / s_l[row];
        const size_t rr = rowbase + row;
        const float4 xv4 = *(const float4*)(x + rr * C_ + c);
        float4 o4;
        o4.x = kval * (ov[0] * linv) + xv4.x;
        o4.y = kval * (ov[1] * linv) + xv4.y;
        o4.z = kval * (ov[2] * linv) + xv4.z;
        o4.w = kval * (ov[3] * linv) + xv4.w;
        *(float4*)(out + rr * (2 * C_) + c) = o4;
    }
}

// ---------- fallback (round-2 vector kernel) if workspace too small ----------
#define ROWS 4
#define FNT  256
__global__ __launch_bounds__(FNT, 2) void attn_fallback(
    const float* __restrict__ g, const float* __restrict__ x,
    const float* __restrict__ xq, const float* __restrict__ pg,
    const float* __restrict__ xv, const float* __restrict__ kk,
    float* __restrict__ out)
{
    __shared__ __align__(16) float s_pg[ROWS][D_];
    __shared__ __align__(16) float s_sc[N_ * ROWS];
    __shared__ float s_rmax[4][ROWS];
    __shared__ float s_rsum[4][ROWS];

    const int t = threadIdx.x, lane = t & 63, w = t >> 6, blk = blockIdx.x;
    const int b = blk >> 10, i0 = (blk & 1023) * ROWS;
    const size_t rowbase = (size_t)b * N_ + i0;
    {
        const int r = t >> 6, cc = (t & 63) * 4;
        const float4 gv = *(const float4*)(g + (rowbase + r) * C_ + cc);
        *(float4*)(out + (rowbase + r) * (2 * C_) + C_ + cc) = gv;
    }
    { const int r = t >> 6, d = t & 63; s_pg[r][d] = pg[(rowbase + r) * D_ + d]; }
    __syncthreads();
    const float* qb = xq + (size_t)b * N_ * D_;
    float lmax[ROWS];
#pragma unroll
    for (int r = 0; r < ROWS; ++r) lmax[r] = -1e30f;
    for (int jj = 0; jj < N_ / FNT; ++jj) {
        const int j = t + jj * FNT;
        const float4* q4p = (const float4*)(qb + (size_t)j * D_);
        float s[ROWS] = {0.f, 0.f, 0.f, 0.f};
#pragma unroll
        for (int u = 0; u < D_ / 8; ++u) {
            const float4 qa = q4p[u * 2], qc = q4p[u * 2 + 1];
#pragma unroll
            for (int r = 0; r < ROWS; ++r) {
                const float4 pa = *(const float4*)&s_pg[r][u * 8];
                const float4 pb = *(const float4*)&s_pg[r][u * 8 + 4];
                s[r] += qa.x * pa.x + qa.y * pa.y + qa.z * pa.z + qa.w * pa.w
                      + qc.x * pb.x + qc.y * pb.y + qc.z * pb.z + qc.w * pb.w;
            }
        }
        *(float4*)&s_sc[j * ROWS] = make_float4(s[0], s[1], s[2], s[3]);
#pragma unroll
        for (int r = 0; r < ROWS; ++r) lmax[r] = fmaxf(lmax[r], s[r]);
    }
#pragma unroll
    for (int r = 0; r < ROWS; ++r) {
        float m = lmax[r];
        for (int o = 32; o > 0; o >>= 1) m = fmaxf(m, __shfl_down(m, o));
        if (lane == 0) s_rmax[w][r] = m;
    }
    __syncthreads();
    float bmax[ROWS];
#pragma unroll
    for (int r = 0; r < ROWS; ++r)
        bmax[r] = fmaxf(fmaxf(s_rmax[0][r], s_rmax[1][r]), fmaxf(s_rmax[2][r], s_rmax[3][r]));
    float lsum[ROWS] = {0.f, 0.f, 0.f, 0.f};
    for (int jj = 0; jj < N_ / FNT; ++jj) {
        const int j = t + jj * FNT;
        float4 s4 = *(const float4*)&s_sc[j * ROWS];
        s4.x = __expf(s4.x - bmax[0]); s4.y = __expf(s4.y - bmax[1]);
        s4.z = __expf(s4.z - bmax[2]); s4.w = __expf(s4.w - bmax[3]);
        *(float4*)&s_sc[j * ROWS] = s4;
        lsum[0] += s4.x; lsum[1] += s4.y; lsum[2] += s4.z; lsum[3] += s4.w;
    }
#pragma unroll
    for (int r = 0; r < ROWS; ++r) {
        float sm = lsum[r];
        for (int o = 32; o > 0; o >>= 1) sm += __shfl_down(sm, o);
        if (lane == 0) s_rsum[w][r] = sm;
    }
    __syncthreads();
    float rinv[ROWS];
#pragma unroll
    for (int r = 0; r < ROWS; ++r)
        rinv[r] = 1.f / (s_rsum[0][r] + s_rsum[1][r] + s_rsum[2][r] + s_rsum[3][r]);
    const int jg = lane >> 4;
    const int c0 = (w * 16 + (lane & 15)) * 4;
    const float* vb = xv + (size_t)b * N_ * C_;
    float acc[ROWS][4];
#pragma unroll
    for (int r = 0; r < ROWS; ++r)
#pragma unroll
        for (int q = 0; q < 4; ++q) acc[r][q] = 0.f;
#pragma unroll 4
    for (int jj = 0; jj < N_ / 4; ++jj) {
        const int j = jj * 4 + jg;
        const float4 p4 = *(const float4*)&s_sc[j * ROWS];
        const float4 v4 = *(const float4*)(vb + (size_t)j * C_ + c0);
        acc[0][0] += p4.x * v4.x; acc[0][1] += p4.x * v4.y; acc[0][2] += p4.x * v4.z; acc[0][3] += p4.x * v4.w;
        acc[1][0] += p4.y * v4.x; acc[1][1] += p4.y * v4.y; acc[1][2] += p4.y * v4.z; acc[1][3] += p4.y * v4.w;
        acc[2][0] += p4.z * v4.x; acc[2][1] += p4.z * v4.y; acc[2][2] += p4.z * v4.z; acc[2][3] += p4.z * v4.w;
        acc[3][0] += p4.w * v4.x; acc[3][1] += p4.w * v4.y; acc[3][2] += p4.w * v4.z; acc[3][3] += p4.w * v4.w;
    }
#pragma unroll
    for (int r = 0; r < ROWS; ++r)
#pragma unroll
        for (int q = 0; q < 4; ++q) {
            acc[r][q] += __shfl_xor(acc[r][q], 16);
            acc[r][q] += __shfl_xor(acc[r][q], 32);
        }
    const float kval = kk[0];
    if (lane < 16) {
        const int c = (w * 16 + lane) * 4;
#pragma unroll
        for (int r = 0; r < ROWS; ++r) {
            const float4 xv4 = *(const float4*)(x + (rowbase + r) * C_ + c);
            float4 ov;
            ov.x = kval * (acc[r][0] * rinv[r]) + xv4.x;
            ov.y = kval * (acc[r][1] * rinv[r]) + xv4.y;
            ov.z = kval * (acc[r][2] * rinv[r]) + xv4.z;
            ov.w = kval * (acc[r][3] * rinv[r]) + xv4.w;
            *(float4*)(out + (rowbase + r) * (2 * C_) + c) = ov;
        }
    }
}

extern "C" void kernel_launch(void* const* d_in, const int* in_sizes, int n_in,
                              void* d_out, int out_size, void* d_ws, size_t ws_size,
                              hipStream_t stream) {
    const float* g  = (const float*)d_in[0];
    const float* x  = (const float*)d_in[1];
    const float* xq = (const float*)d_in[2];
    const float* pg = (const float*)d_in[3];
    const float* xv = (const float*)d_in[4];
    const float* kk = (const float*)d_in[5];
    float* out = (float*)d_out;

    const int B = in_sizes[0] / (N_ * C_);   // 4
    const size_t qn = (size_t)B * N_ * D_;
    const size_t vn = (size_t)B * N_ * C_;
    const size_t need = (2 * qn + vn) * sizeof(unsigned short);

    if (B != 4 || ws_size < need) {
        attn_fallback<<<dim3(B * (N_ / ROWS)), FNT, 0, stream>>>(g, x, xq, pg, xv, kk, out);
        return;
    }

    unsigned short* qbf  = (unsigned short*)d_ws;
    unsigned short* pgbf = qbf + qn;
    unsigned short* vt2  = pgbf + qn;

    prepass_kernel<<<dim3(512 + B * 512), 256, 0, stream>>>(xq, pg, xv, qbf, pgbf, vt2);
    attn_main<<<dim3(B * (N_ / 64)), 512, 0, stream>>>(g, x, kk, out, qbf, pgbf, vt2);
}